// Round 4
// baseline (619.473 us; speedup 1.0000x reference)
//
#include <hip/hip_runtime.h>
#include <hip/hip_bf16.h>
#include <math.h>

#define Dd   512
#define Hn   8
#define Bn   2
#define Ln   4096
#define NPn  2048
#define INV_T 1.42857142857142857f   // 1/0.7

typedef __attribute__((ext_vector_type(8))) short short8;   // 8 bf16 = 4 VGPR
typedef __attribute__((ext_vector_type(4))) float f32x4;

__device__ __forceinline__ ushort bf16_rne(float x) {
    uint u = __builtin_bit_cast(uint, x);
    return (ushort)((u + 0x7fffu + ((u >> 16) & 1u)) >> 16);
}
__device__ __forceinline__ float bf16_tof(ushort h) {
    uint u = ((uint)h) << 16; return __builtin_bit_cast(float, u);
}

// ---------------------------------------------------------------------------
// LayerNorm + hi/lo bf16 split. One wave per row of 512.
// ---------------------------------------------------------------------------
__global__ __launch_bounds__(64) void ln_split(
    const float* __restrict__ x, const float* __restrict__ qsrc,
    const float* __restrict__ gx, const float* __restrict__ bx,
    const float* __restrict__ gq, const float* __restrict__ bq,
    ushort* __restrict__ xh, ushort* __restrict__ xl,
    ushort* __restrict__ qnh, ushort* __restrict__ qnl)
{
    int row = blockIdx.x;
    const float* src; ushort* dh; ushort* dl; const float* g; const float* be;
    if (row < Bn * Ln) {
        src = x + (size_t)row * Dd; dh = xh + (size_t)row * Dd; dl = xl + (size_t)row * Dd;
        g = gx; be = bx;
    } else {
        int r = row - Bn * Ln;
        src = qsrc + (size_t)r * Dd; dh = qnh + (size_t)r * Dd; dl = qnl + (size_t)r * Dd;
        g = gq; be = bq;
    }
    int t = threadIdx.x;
    float4 v0 = ((const float4*)src)[2 * t];
    float4 v1 = ((const float4*)src)[2 * t + 1];
    float s = v0.x + v0.y + v0.z + v0.w + v1.x + v1.y + v1.z + v1.w;
#pragma unroll
    for (int o = 32; o > 0; o >>= 1) s += __shfl_down(s, o);
    float mu = __shfl(s, 0) * (1.0f / Dd);
    float a[8] = {v0.x - mu, v0.y - mu, v0.z - mu, v0.w - mu,
                  v1.x - mu, v1.y - mu, v1.z - mu, v1.w - mu};
    float s2 = 0.f;
#pragma unroll
    for (int i = 0; i < 8; ++i) s2 += a[i] * a[i];
#pragma unroll
    for (int o = 32; o > 0; o >>= 1) s2 += __shfl_down(s2, o);
    float rstd = rsqrtf(__shfl(s2, 0) * (1.0f / Dd) + 1e-5f);
    float4 g0 = ((const float4*)g)[2 * t],  g1 = ((const float4*)g)[2 * t + 1];
    float4 b0 = ((const float4*)be)[2 * t], b1 = ((const float4*)be)[2 * t + 1];
    float gv[8] = {g0.x, g0.y, g0.z, g0.w, g1.x, g1.y, g1.z, g1.w};
    float bv[8] = {b0.x, b0.y, b0.z, b0.w, b1.x, b1.y, b1.z, b1.w};
    ushort hv[8], lv[8];
#pragma unroll
    for (int i = 0; i < 8; ++i) {
        float v = a[i] * rstd * gv[i] + bv[i];
        hv[i] = bf16_rne(v);
        lv[i] = bf16_rne(v - bf16_tof(hv[i]));
    }
    *(ushort4*)&dh[t * 8]     = make_ushort4(hv[0], hv[1], hv[2], hv[3]);
    *(ushort4*)&dh[t * 8 + 4] = make_ushort4(hv[4], hv[5], hv[6], hv[7]);
    *(ushort4*)&dl[t * 8]     = make_ushort4(lv[0], lv[1], lv[2], lv[3]);
    *(ushort4*)&dl[t * 8 + 4] = make_ushort4(lv[4], lv[5], lv[6], lv[7]);
}

// ---------------------------------------------------------------------------
// Weight split: wq, wk (f32 512x512) -> hi/lo bf16.
// ---------------------------------------------------------------------------
__global__ __launch_bounds__(256) void wsplit(
    const float* __restrict__ wq, const float* __restrict__ wk,
    ushort* __restrict__ wqh, ushort* __restrict__ wql,
    ushort* __restrict__ wkh, ushort* __restrict__ wkl)
{
    int i = blockIdx.x * 256 + threadIdx.x;
    const float* src; ushort* dh; ushort* dl;
    int j = i;
    if (i < 65536) { src = wq; dh = wqh; dl = wql; }
    else { j -= 65536; src = wk; dh = wkh; dl = wkl; }
    float4 v = ((const float4*)src)[j];
    float vv[4] = {v.x, v.y, v.z, v.w};
    ushort hv[4], lv[4];
#pragma unroll
    for (int k = 0; k < 4; ++k) {
        hv[k] = bf16_rne(vv[k]);
        lv[k] = bf16_rne(vv[k] - bf16_tof(hv[k]));
    }
    *(ushort4*)&dh[j * 4] = make_ushort4(hv[0], hv[1], hv[2], hv[3]);
    *(ushort4*)&dl[j * 4] = make_ushort4(lv[0], lv[1], lv[2], lv[3]);
}

// ---------------------------------------------------------------------------
// Projection GEMM, split-bf16 MFMA.
// ---------------------------------------------------------------------------
__global__ __launch_bounds__(256, 2) void proj_mfma(
    const ushort* __restrict__ Ah, const ushort* __restrict__ Al,
    const ushort* __restrict__ Wh, const ushort* __restrict__ Wl,
    const float* __restrict__ bias,
    ushort* __restrict__ Chi, ushort* __restrict__ Clo, float scale)
{
    int bm = blockIdx.x * 64, bn = blockIdx.y * 256;
    int t = threadIdx.x, wv = t >> 6, ln = t & 63;
    int lq = ln & 15, lg = ln >> 4;
    f32x4 acc[4][4] = {};
    for (int k0 = 0; k0 < Dd; k0 += 32) {
        short8 bh[4], bl[4];
#pragma unroll
        for (int nf = 0; nf < 4; ++nf) {
            size_t wr = (size_t)(bn + wv * 64 + nf * 16 + lq) * Dd + k0 + lg * 8;
            bh[nf] = *(const short8*)&Wh[wr];
            bl[nf] = *(const short8*)&Wl[wr];
        }
#pragma unroll
        for (int qt = 0; qt < 4; ++qt) {
            size_t ar = (size_t)(bm + qt * 16 + lq) * Dd + k0 + lg * 8;
            short8 ah = *(const short8*)&Ah[ar];
            short8 al = *(const short8*)&Al[ar];
#pragma unroll
            for (int nf = 0; nf < 4; ++nf) {
                acc[qt][nf] = __builtin_amdgcn_mfma_f32_16x16x32_bf16(ah, bh[nf], acc[qt][nf], 0, 0, 0);
                acc[qt][nf] = __builtin_amdgcn_mfma_f32_16x16x32_bf16(ah, bl[nf], acc[qt][nf], 0, 0, 0);
                acc[qt][nf] = __builtin_amdgcn_mfma_f32_16x16x32_bf16(al, bh[nf], acc[qt][nf], 0, 0, 0);
            }
        }
    }
    float bb[4];
#pragma unroll
    for (int nf = 0; nf < 4; ++nf) bb[nf] = bias[bn + wv * 64 + nf * 16 + lq];
#pragma unroll
    for (int qt = 0; qt < 4; ++qt)
#pragma unroll
        for (int nf = 0; nf < 4; ++nf)
#pragma unroll
            for (int r = 0; r < 4; ++r) {
                int m = bm + qt * 16 + lg * 4 + r;
                int n = bn + wv * 64 + nf * 16 + lq;
                float v = scale * (acc[qt][nf][r] + bb[nf]);
                ushort hi = bf16_rne(v);
                Chi[(size_t)m * Dd + n] = hi;
                Clo[(size_t)m * Dd + n] = bf16_rne(v - bf16_tof(hi));
            }
}

// ---------------------------------------------------------------------------
// Transpose hi/lo (packed u32): [B][L][D] -> [B][D][L].
// ---------------------------------------------------------------------------
__global__ __launch_bounds__(256) void transpose_u16(
    const ushort* __restrict__ xh, const ushort* __restrict__ xl,
    ushort* __restrict__ vh, ushort* __restrict__ vl)
{
    __shared__ uint tile[64][65];
    int l0 = blockIdx.x * 64, d0 = blockIdx.y * 64, b = blockIdx.z;
    int t = threadIdx.x;
#pragma unroll
    for (int i = 0; i < 16; ++i) {
        int idx = i * 256 + t, lr = idx >> 6, lc = idx & 63;
        size_t o = ((size_t)(b * Ln + l0 + lr)) * Dd + d0 + lc;
        tile[lr][lc] = (uint)xh[o] | ((uint)xl[o] << 16);
    }
    __syncthreads();
#pragma unroll
    for (int i = 0; i < 16; ++i) {
        int idx = i * 256 + t, dr = idx >> 6, lc = idx & 63;
        uint v = tile[lc][dr];
        size_t o = ((size_t)(b * Dd + d0 + dr)) * Ln + l0 + lc;
        vh[o] = (ushort)(v & 0xffff);
        vl[o] = (ushort)(v >> 16);
    }
}

// 6-MFMA split score: S += Qhi*Khi + Qhi*Klo + Qlo*Khi (both k-halves).
#define MFMA6(acc, ah0, ah1, al0, al1, bh0, bh1, bl0, bl1)                         \
    acc = __builtin_amdgcn_mfma_f32_16x16x32_bf16(ah0, bh0, acc, 0, 0, 0);         \
    acc = __builtin_amdgcn_mfma_f32_16x16x32_bf16(ah0, bl0, acc, 0, 0, 0);         \
    acc = __builtin_amdgcn_mfma_f32_16x16x32_bf16(al0, bh0, acc, 0, 0, 0);         \
    acc = __builtin_amdgcn_mfma_f32_16x16x32_bf16(ah1, bh1, acc, 0, 0, 0);         \
    acc = __builtin_amdgcn_mfma_f32_16x16x32_bf16(ah1, bl1, acc, 0, 0, 0);         \
    acc = __builtin_amdgcn_mfma_f32_16x16x32_bf16(al1, bh1, acc, 0, 0, 0);

// ---------------------------------------------------------------------------
// Pass 1: zpart[(ck*2+b)][q][h] partial sums of exp(s) over 512-key chunks.
// Grid 2048: combo = orig&31 -> (b, ck 0..7, h-group 0/1); q0 = (orig>>5)*32.
// 4 waves; wave = ONE head (h = hg*4+wv); Q frags in registers; K-frag loads
// register-double-buffered (1-deep prefetch).
// ---------------------------------------------------------------------------
__global__ __launch_bounds__(256, 4) void attn_pass1(
    const ushort* __restrict__ qh_g, const ushort* __restrict__ ql_g,
    const ushort* __restrict__ kh_g, const ushort* __restrict__ kl_g,
    float* __restrict__ zpart)
{
    int orig = blockIdx.x;
    int combo = orig & 31, b = combo & 1, ck = (combo >> 1) & 7, hg = combo >> 4;
    int q0 = (orig >> 5) * 32;
    int t = threadIdx.x, wv = t >> 6, ln = t & 63;
    int lq = ln & 15, lg = ln >> 4;
    int h = hg * 4 + wv;

    short8 AH[2][2], AL[2][2];   // [qt][khalf]
#pragma unroll
    for (int qt = 0; qt < 2; ++qt)
#pragma unroll
        for (int hf = 0; hf < 2; ++hf) {
            size_t a = (size_t)(q0 + qt * 16 + lq) * Dd + h * 64 + hf * 32 + lg * 8;
            AH[qt][hf] = __builtin_nontemporal_load((const short8*)&qh_g[a]);
            AL[qt][hf] = __builtin_nontemporal_load((const short8*)&ql_g[a]);
        }

    float z[2][4] = {};
    const short* kh_p = (const short*)kh_g + ((size_t)(b * Ln + ck * 512 + lq)) * Dd + h * 64 + lg * 8;
    const short* kl_p = (const short*)kl_g + ((size_t)(b * Ln + ck * 512 + lq)) * Dd + h * 64 + lg * 8;

#define LOADK1(B0, B1, B2, B3, s)                                                  \
    B0 = *(const short8*)&kh_p[(size_t)(s) * 16 * Dd];                             \
    B1 = *(const short8*)&kh_p[(size_t)(s) * 16 * Dd + 32];                        \
    B2 = *(const short8*)&kl_p[(size_t)(s) * 16 * Dd];                             \
    B3 = *(const short8*)&kl_p[(size_t)(s) * 16 * Dd + 32];

#define STEP1(B0, B1, B2, B3)                                                      \
    {                                                                              \
        f32x4 acc0 = {}, acc1 = {};                                                \
        MFMA6(acc0, AH[0][0], AH[0][1], AL[0][0], AL[0][1], B0, B1, B2, B3);       \
        MFMA6(acc1, AH[1][0], AH[1][1], AL[1][0], AL[1][1], B0, B1, B2, B3);       \
        _Pragma("unroll")                                                          \
        for (int r = 0; r < 4; ++r) {                                              \
            z[0][r] += __expf(acc0[r]);                                            \
            z[1][r] += __expf(acc1[r]);                                            \
        }                                                                          \
    }

    short8 A0, A1, A2, A3, B0, B1, B2, B3;
    LOADK1(A0, A1, A2, A3, 0);
    for (int s = 0; s < 32; s += 2) {
        LOADK1(B0, B1, B2, B3, s + 1);
        STEP1(A0, A1, A2, A3);
        if (s + 2 < 32) { LOADK1(A0, A1, A2, A3, s + 2); }
        STEP1(B0, B1, B2, B3);
    }

#pragma unroll
    for (int qt = 0; qt < 2; ++qt)
#pragma unroll
        for (int r = 0; r < 4; ++r) {
            float v = z[qt][r];
            v += __shfl_xor(v, 1); v += __shfl_xor(v, 2);
            v += __shfl_xor(v, 4); v += __shfl_xor(v, 8);
            z[qt][r] = v;
        }
    if (lq == 0) {
#pragma unroll
        for (int qt = 0; qt < 2; ++qt)
#pragma unroll
            for (int r = 0; r < 4; ++r) {
                int q = q0 + qt * 16 + lg * 4 + r;
                zpart[((size_t)(ck * 2 + b) * NPn + q) * 8 + h] = z[qt][r];
            }
    }
}

// izs[b][q][h] = 1 / (8 * sum_ck zpart)
__global__ __launch_bounds__(256) void zreduce(
    const float* __restrict__ zpart, float* __restrict__ izs)
{
    int g = blockIdx.x * 256 + threadIdx.x;   // 32768
    int b = g >> 14, q = (g >> 3) & 2047, h = g & 7;
    float s = 0.f;
#pragma unroll
    for (int c = 0; c < 8; ++c)
        s += zpart[((size_t)(c * 2 + b) * NPn + q) * 8 + h];
    izs[g] = 1.0f / (8.0f * s);
}

// ---------------------------------------------------------------------------
// Pass 2: 32-q tile x 1024-key chunk per block. Grid 512: combo = orig&7 ->
// (b, ck) pinned per XCD; kt-outer / h-inner with register-double-buffered
// K frags; nontemporal Opart stores & Q loads (keep L2 = K/V only).
// ---------------------------------------------------------------------------
__global__ __launch_bounds__(512, 4) void attn_pass2(
    const ushort* __restrict__ qh_g, const ushort* __restrict__ ql_g,
    const ushort* __restrict__ kh_g, const ushort* __restrict__ kl_g,
    const ushort* __restrict__ vh_g, const ushort* __restrict__ vl_g,
    const float* __restrict__ izs,
    float* __restrict__ Opart, float* __restrict__ rpart)
{
    __shared__ __align__(16) short8 qhs[2048];   // 32 q x 64 c8, swizzled
    __shared__ __align__(16) short8 qls[2048];
    __shared__ __align__(16) ushort Ps[32 * 128];
    __shared__ float izss[256];
    __shared__ float rss[8][32];

    int orig = blockIdx.x;
    int combo = orig & 7, b = combo & 1, ck = combo >> 1;
    int q0 = (orig >> 3) * 32;
    int t = threadIdx.x, wv = t >> 6, ln = t & 63;
    int lq = ln & 15, lg = ln >> 4;
    const short8* qh8 = (const short8*)qh_g;
    const short8* ql8 = (const short8*)ql_g;
    const short8* Ps8 = (const short8*)Ps;

#pragma unroll
    for (int it = 0; it < 4; ++it) {
        int idx = it * 512 + t; int r = idx >> 6;
        int slot = idx ^ (r & 7);
        qhs[slot] = __builtin_nontemporal_load(&qh8[(size_t)(q0 + r) * 64 + (idx & 63)]);
        qls[slot] = __builtin_nontemporal_load(&ql8[(size_t)(q0 + r) * 64 + (idx & 63)]);
    }
    if (t < 256) izss[t] = izs[((size_t)b * NPn + q0 + (t >> 3)) * 8 + (t & 7)];
    __syncthreads();

    f32x4 oacc[2][4] = {};            // [qt][n]
    float racc[2][4] = {};            // [qt][r]

// Q frags for head hh, both q-tiles, then 2x MFMA6 against B0..B3.
#define QK_H(acc0, acc1, B0, B1, B2, B3, hh)                                       \
    {                                                                              \
        int bse = lq * 64 + (hh) * 8;                                              \
        int sw = lq & 7;                                                           \
        short8 a0h0 = qhs[(bse + lg) ^ sw];                                        \
        short8 a0h1 = qhs[(bse + 4 + lg) ^ sw];                                    \
        short8 a0l0 = qls[(bse + lg) ^ sw];                                        \
        short8 a0l1 = qls[(bse + 4 + lg) ^ sw];                                    \
        short8 a1h0 = qhs[(bse + 1024 + lg) ^ sw];                                 \
        short8 a1h1 = qhs[(bse + 1024 + 4 + lg) ^ sw];                             \
        short8 a1l0 = qls[(bse + 1024 + lg) ^ sw];                                 \
        short8 a1l1 = qls[(bse + 1024 + 4 + lg) ^ sw];                             \
        MFMA6(acc0, a0h0, a0h1, a0l0, a0l1, B0, B1, B2, B3);                       \
        MFMA6(acc1, a1h0, a1h1, a1l0, a1l1, B0, B1, B2, B3);                       \
    }

#define LOADK2(B0, B1, B2, B3, hh)                                                 \
    B0 = *(const short8*)&kRh[(hh) * 64];                                          \
    B1 = *(const short8*)&kRh[(hh) * 64 + 32];                                     \
    B2 = *(const short8*)&kRl[(hh) * 64];                                          \
    B3 = *(const short8*)&kRl[(hh) * 64 + 32];

    for (int g = 0; g < 4; ++g) {     // 256-key groups
        int t0 = ck * 1024 + g * 256;
        size_t krow = ((size_t)(b * Ln + t0 + wv * 16 + lq)) * Dd + lg * 8;
#pragma unroll
        for (int kt = 0; kt < 2; ++kt) {
            const short* kRh = (const short*)kh_g + krow + (size_t)kt * 128 * Dd;
            const short* kRl = (const short*)kl_g + krow + (size_t)kt * 128 * Dd;
            float p0[4] = {}, p1[4] = {};
            short8 A0, A1, A2, A3, B0, B1, B2, B3;
            LOADK2(A0, A1, A2, A3, 0);
#pragma unroll
            for (int h = 0; h < 8; h += 2) {
                LOADK2(B0, B1, B2, B3, h + 1);
                {
                    f32x4 acc0 = {}, acc1 = {};
                    QK_H(acc0, acc1, A0, A1, A2, A3, h);
#pragma unroll
                    for (int r = 0; r < 4; ++r) {
                        p0[r] += __expf(acc0[r]) * izss[(lg * 4 + r) * 8 + h];
                        p1[r] += __expf(acc1[r]) * izss[(16 + lg * 4 + r) * 8 + h];
                    }
                }
                if (h + 2 < 8) { LOADK2(A0, A1, A2, A3, h + 2); }
                {
                    f32x4 acc0 = {}, acc1 = {};
                    QK_H(acc0, acc1, B0, B1, B2, B3, h + 1);
#pragma unroll
                    for (int r = 0; r < 4; ++r) {
                        p0[r] += __expf(acc0[r]) * izss[(lg * 4 + r) * 8 + h + 1];
                        p1[r] += __expf(acc1[r]) * izss[(16 + lg * 4 + r) * 8 + h + 1];
                    }
                }
            }
#pragma unroll
            for (int r = 0; r < 4; ++r) {
                {
                    int q = lg * 4 + r;
                    float wgt = __expf(INV_T * __logf(p0[r]));
                    ushort uw = bf16_rne(wgt);
                    racc[0][r] += bf16_tof(uw);
                    Ps[(q * 128 + wv * 16 + lq) ^ ((q & 7) << 3)] = uw;
                }
                {
                    int q = 16 + lg * 4 + r;
                    float wgt = __expf(INV_T * __logf(p1[r]));
                    ushort uw = bf16_rne(wgt);
                    racc[1][r] += bf16_tof(uw);
                    Ps[(q * 128 + wv * 16 + lq) ^ ((q & 7) << 3)] = uw;
                }
            }
            __syncthreads();
            short8 pa[2][4];
#pragma unroll
            for (int qt = 0; qt < 2; ++qt)
#pragma unroll
                for (int ks = 0; ks < 4; ++ks) {
                    int row = qt * 16 + lq;
                    pa[qt][ks] = Ps8[(row * 16 + ks * 4 + lg) ^ (row & 7)];
                }
#pragma unroll
            for (int n = 0; n < 4; ++n) {
                size_t vrow = ((size_t)(b * Dd + wv * 64 + n * 16 + lq)) * Ln
                              + t0 + kt * 128 + lg * 8;
                const short* vR = (const short*)vh_g + vrow;
                const short* wR = (const short*)vl_g + vrow;
                short8 v0 = *(const short8*)&vR[0],  v1 = *(const short8*)&vR[32];
                short8 v2 = *(const short8*)&vR[64], v3 = *(const short8*)&vR[96];
                short8 w0 = *(const short8*)&wR[0],  w1 = *(const short8*)&wR[32];
                short8 w2 = *(const short8*)&wR[64], w3 = *(const short8*)&wR[96];
#pragma unroll
                for (int qt = 0; qt < 2; ++qt) {
                    oacc[qt][n] = __builtin_amdgcn_mfma_f32_16x16x32_bf16(pa[qt][0], v0, oacc[qt][n], 0, 0, 0);
                    oacc[qt][n] = __builtin_amdgcn_mfma_f32_16x16x32_bf16(pa[qt][0], w0, oacc[qt][n], 0, 0, 0);
                    oacc[qt][n] = __builtin_amdgcn_mfma_f32_16x16x32_bf16(pa[qt][1], v1, oacc[qt][n], 0, 0, 0);
                    oacc[qt][n] = __builtin_amdgcn_mfma_f32_16x16x32_bf16(pa[qt][1], w1, oacc[qt][n], 0, 0, 0);
                    oacc[qt][n] = __builtin_amdgcn_mfma_f32_16x16x32_bf16(pa[qt][2], v2, oacc[qt][n], 0, 0, 0);
                    oacc[qt][n] = __builtin_amdgcn_mfma_f32_16x16x32_bf16(pa[qt][2], w2, oacc[qt][n], 0, 0, 0);
                    oacc[qt][n] = __builtin_amdgcn_mfma_f32_16x16x32_bf16(pa[qt][3], v3, oacc[qt][n], 0, 0, 0);
                    oacc[qt][n] = __builtin_amdgcn_mfma_f32_16x16x32_bf16(pa[qt][3], w3, oacc[qt][n], 0, 0, 0);
                }
            }
            __syncthreads();
        }
    }

#pragma unroll
    for (int qt = 0; qt < 2; ++qt)
#pragma unroll
        for (int r = 0; r < 4; ++r) {
            float v = racc[qt][r];
            v += __shfl_xor(v, 1); v += __shfl_xor(v, 2);
            v += __shfl_xor(v, 4); v += __shfl_xor(v, 8);
            racc[qt][r] = v;
        }
    if (lq == 0) {
#pragma unroll
        for (int qt = 0; qt < 2; ++qt)
#pragma unroll
            for (int r = 0; r < 4; ++r) rss[wv][qt * 16 + lg * 4 + r] = racc[qt][r];
    }
    __syncthreads();
    if (t < 32) {
        float s = 0.f;
#pragma unroll
        for (int w2 = 0; w2 < 8; ++w2) s += rss[w2][t];
        rpart[(size_t)(ck * 2 + b) * NPn + q0 + t] = s;
    }
#pragma unroll
    for (int qt = 0; qt < 2; ++qt)
#pragma unroll
        for (int n = 0; n < 4; ++n)
#pragma unroll
            for (int r = 0; r < 4; ++r) {
                int q = q0 + qt * 16 + lg * 4 + r;
                int d = wv * 64 + n * 16 + lq;
                __builtin_nontemporal_store(oacc[qt][n][r],
                    &Opart[((size_t)(ck * 2 + b) * NPn + q) * Dd + d]);
            }
}

// out = (sum_ck Opart) / (sum_ck rpart)
__global__ __launch_bounds__(256) void finalize(
    const float* __restrict__ Opart, const float* __restrict__ rpart,
    float* __restrict__ out)
{
    int idx = blockIdx.x * 256 + threadIdx.x;   // f32x4 units
    int d4 = idx & 127, q = (idx >> 7) & 2047, b = idx >> 18;
    float rs = 0.f;
#pragma unroll
    for (int c = 0; c < 4; ++c) rs += rpart[(size_t)(c * 2 + b) * NPn + q];
    f32x4 o = {};
#pragma unroll
    for (int c = 0; c < 4; ++c) {
        f32x4 v = __builtin_nontemporal_load(
            (const f32x4*)Opart + ((size_t)(c * 2 + b) * NPn + q) * 128 + d4);
        o += v;
    }
    float inv = 1.0f / rs;
    ((f32x4*)out)[idx] = o * inv;
}

// ---------------------------------------------------------------------------
extern "C" void kernel_launch(void* const* d_in, const int* in_sizes, int n_in,
                              void* d_out, int out_size, void* d_ws, size_t ws_size,
                              hipStream_t stream)
{
    (void)in_sizes; (void)n_in; (void)out_size; (void)ws_size;
    const float* x       = (const float*)d_in[0];
    const float* queries = (const float*)d_in[1];
    const float* wq      = (const float*)d_in[2];
    const float* wk      = (const float*)d_in[3];
    const float* bq      = (const float*)d_in[4];
    const float* bk      = (const float*)d_in[5];
    const float* gq      = (const float*)d_in[6];
    const float* betq    = (const float*)d_in[7];
    const float* gx      = (const float*)d_in[8];
    const float* betx    = (const float*)d_in[9];

    const size_t XN = (size_t)Bn * Ln * Dd;
    const size_t QN = (size_t)NPn * Dd;
    const size_t WN = (size_t)Dd * Dd;

    ushort* u = (ushort*)d_ws;
    ushort* xh  = u;             ushort* xl  = xh + XN;
    ushort* qnh = xl + XN;       ushort* qnl = qnh + QN;
    ushort* wqh = qnl + QN;      ushort* wql = wqh + WN;
    ushort* wkh = wql + WN;      ushort* wkl = wkh + WN;
    ushort* kh  = wkl + WN;      ushort* kl  = kh + XN;
    ushort* qh  = kl + XN;       ushort* ql  = qh + QN;
    ushort* vh  = ql + QN;       ushort* vl  = vh + XN;
    float* f = (float*)(vl + XN);
    float* zpart = f;                            // 16*2048*8
    float* izs   = zpart + 262144;
    float* rpart = izs + 32768;
    float* Opart = rpart + 16384;                // 8*2048*512

    ln_split<<<Bn * Ln + NPn, 64, 0, stream>>>(x, queries, gx, betx, gq, betq,
                                               xh, xl, qnh, qnl);
    wsplit<<<512, 256, 0, stream>>>(wq, wk, wqh, wql, wkh, wkl);
    proj_mfma<<<dim3((Bn * Ln) / 64, 2), 256, 0, stream>>>(xh, xl, wkh, wkl, bk, kh, kl, 1.0f);
    proj_mfma<<<dim3(NPn / 64, 2), 256, 0, stream>>>(qnh, qnl, wqh, wql, bq, qh, ql, 0.125f);
    transpose_u16<<<dim3(Ln / 64, Dd / 64, Bn), 256, 0, stream>>>(xh, xl, vh, vl);
    attn_pass1<<<2048, 256, 0, stream>>>(qh, ql, kh, kl, zpart);
    zreduce<<<128, 256, 0, stream>>>(zpart, izs);
    attn_pass2<<<512, 512, 0, stream>>>(qh, ql, kh, kl, vh, vl, izs, Opart, rpart);
    finalize<<<2048, 256, 0, stream>>>(Opart, rpart, (float*)d_out);
}